// Round 12
// baseline (191.579 us; speedup 1.0000x reference)
//
#include <hip/hip_runtime.h>

#define Bsz 4
#define SEQ 2048
#define DIM 1024
#define NH 16
#define HD 64

typedef float  f32x4  __attribute__((ext_vector_type(4)));
typedef __bf16 bf16x8 __attribute__((ext_vector_type(8)));
typedef __bf16 bf16x4 __attribute__((ext_vector_type(4)));
typedef short  s16x4  __attribute__((ext_vector_type(4)));

__device__ __forceinline__ f32x4 mfma16(bf16x8 a, bf16x8 b, f32x4 c) {
    return __builtin_amdgcn_mfma_f32_16x16x32_bf16(a, b, c, 0, 0, 0);
}
__device__ __forceinline__ f32x4 mfma16k16(bf16x4 a, bf16x4 b, f32x4 c) {
#if defined(__has_builtin) && __has_builtin(__builtin_amdgcn_mfma_f32_16x16x16bf16_1k)
    return __builtin_amdgcn_mfma_f32_16x16x16bf16_1k(
        __builtin_bit_cast(s16x4, a), __builtin_bit_cast(s16x4, b), c, 0, 0, 0);
#else
    asm volatile("s_nop 2\n\tv_mfma_f32_16x16x16_bf16 %0, %1, %2, %0\n\ts_nop 7\n\ts_nop 7"
                 : "+v"(c) : "v"(a), "v"(b));
    return c;
#endif
}

// bare HW exp2 (single v_exp_f32)
__device__ __forceinline__ float fast_exp2(float x) {
#if defined(__has_builtin) && __has_builtin(__builtin_amdgcn_exp2f)
    return __builtin_amdgcn_exp2f(x);
#else
    return exp2f(x);
#endif
}

#define GLD_LDS16(gsrc, ldst)                                                        \
    __builtin_amdgcn_global_load_lds(                                                \
        (const __attribute__((address_space(1))) void*)(gsrc),                       \
        (__attribute__((address_space(3))) void*)(ldst), 16, 0, 0)

// ---------------------------------------------------------------------------
// Kernel 0: fp32 -> bf16 convert of the three X inputs (streaming, 8 el/thr)
// ---------------------------------------------------------------------------
__global__ __launch_bounds__(256) void cvt_kernel(
    const float* __restrict__ x0, const float* __restrict__ x1,
    const float* __restrict__ x2,
    __bf16* __restrict__ o0, __bf16* __restrict__ o1, __bf16* __restrict__ o2)
{
    int z = blockIdx.y;
    const float* X = (z == 0) ? x0 : (z == 1) ? x1 : x2;
    __bf16*      O = (z == 0) ? o0 : (z == 1) ? o1 : o2;
    size_t i = ((size_t)blockIdx.x * 256 + threadIdx.x) * 8;
    f32x4 a = *(const f32x4*)(X + i);
    f32x4 b = *(const f32x4*)(X + i + 4);
    bf16x8 r;
#pragma unroll
    for (int j = 0; j < 4; j++) { r[j] = (__bf16)a[j]; r[4 + j] = (__bf16)b[j]; }
    *(bf16x8*)(O + i) = r;
}

// ---------------------------------------------------------------------------
// Kernel 1: transpose + convert weights fp32 [K][N] -> bf16 Wt [N][K]
// ---------------------------------------------------------------------------
__global__ __launch_bounds__(256) void wt_kernel(
    const float* __restrict__ Wq, const float* __restrict__ Wk,
    const float* __restrict__ Wv, const float* __restrict__ Wo,
    __bf16* __restrict__ wt)
{
    __shared__ float tile[64][65];
    int z = blockIdx.z;
    const float* W = (z == 0) ? Wq : (z == 1) ? Wk : (z == 2) ? Wv : Wo;
    __bf16* out = wt + (size_t)z * DIM * DIM;
    int kb = blockIdx.x * 64, nb = blockIdx.y * 64;
    int t = threadIdx.x;
    int cidx = t & 63, ridx = t >> 6;
#pragma unroll
    for (int i = 0; i < 16; i++) {
        int r = ridx + i * 4;
        tile[r][cidx] = W[(size_t)(kb + r) * DIM + nb + cidx];
    }
    __syncthreads();
#pragma unroll
    for (int i = 0; i < 16; i++) {
        int r = ridx + i * 4;
        out[(size_t)(nb + r) * DIM + kb + cidx] = (__bf16)tile[cidx][r];
    }
}

// ---------------------------------------------------------------------------
// Kernel 2 (fast path): projection GEMM, all-bf16, 4x global_load_lds,
// dbuf, 1 barrier/K-step (round-8 proven structure).
// z=2 (V): transposed-per-head store via 2-pass LDS tile aliasing staging.
// ---------------------------------------------------------------------------
__global__ __launch_bounds__(256, 2) void gemm_proj(
    const __bf16* __restrict__ Xq, const __bf16* __restrict__ Xk,
    const __bf16* __restrict__ Xv, const __bf16* __restrict__ wt,
    const float* __restrict__ bq, const float* __restrict__ bk,
    const float* __restrict__ bv,
    __bf16* __restrict__ oq, __bf16* __restrict__ ok, __bf16* __restrict__ ovT)
{
    int z = blockIdx.z;
    const __bf16* X    = (z == 0) ? Xq : (z == 1) ? Xk : Xv;
    const float*  bias = (z == 0) ? bq : (z == 1) ? bk : bv;
    const __bf16* Bt   = wt + (size_t)z * DIM * DIM;

    __shared__ __align__(16) char smem[32768];
    __bf16* const Ab = (__bf16*)smem;               // [2][4096]
    __bf16* const Bb = (__bf16*)(smem + 16384);     // [2][4096]

    int m0 = blockIdx.x * 128, n0 = blockIdx.y * 128;
    int tid = threadIdx.x, lane = tid & 63, w = tid >> 6;
    int c = lane & 15, g = lane >> 4;
    int wm = (w >> 1) * 64, wn = (w & 1) * 64;

    f32x4 acc[4][4] = {};

    int srow = (w * 2) * 16 + (lane >> 2);
    int scol = (lane & 3) * 8;
    const __bf16* aptr0 = X + (size_t)(m0 + srow) * DIM + scol;
    const __bf16* aptr1 = aptr0 + (size_t)16 * DIM;
    const __bf16* bptr0 = Bt + (size_t)(n0 + srow) * DIM + scol;
    const __bf16* bptr1 = bptr0 + (size_t)16 * DIM;
    int so0 = (w * 2) * 512;
    int so1 = (w * 2 + 1) * 512;

    GLD_LDS16(aptr0, Ab + so0);
    GLD_LDS16(aptr1, Ab + so1);
    GLD_LDS16(bptr0, Bb + so0);
    GLD_LDS16(bptr1, Bb + so1);
    __syncthreads();

    int cur = 0;
    for (int kt = 0; kt < 32; ++kt) {
        int nxt = kt + 1;
        int nb = cur ^ 1;
        if (nxt < 32) {
            int k0 = nxt * 32;
            GLD_LDS16(aptr0 + k0, Ab + nb * 4096 + so0);
            GLD_LDS16(aptr1 + k0, Ab + nb * 4096 + so1);
            GLD_LDS16(bptr0 + k0, Bb + nb * 4096 + so0);
            GLD_LDS16(bptr1 + k0, Bb + nb * 4096 + so1);
        }
        bf16x8 af[4], bf[4];
#pragma unroll
        for (int mf = 0; mf < 4; mf++)
            af[mf] = *(bf16x8*)&Ab[cur * 4096 + (wm + mf * 16 + c) * 32 + g * 8];
#pragma unroll
        for (int nf = 0; nf < 4; nf++)
            bf[nf] = *(bf16x8*)&Bb[cur * 4096 + (wn + nf * 16 + c) * 32 + g * 8];
#pragma unroll
        for (int mf = 0; mf < 4; mf++)
#pragma unroll
            for (int nf = 0; nf < 4; nf++)
                acc[mf][nf] = mfma16(af[mf], bf[nf], acc[mf][nf]);
        __syncthreads();
        cur = nb;
    }

    if (z == 2) {
        __bf16* T = (__bf16*)smem + (size_t)w * 2304;   // 64 x 36 elems/wave
        int h = (n0 + wn) >> 6;
        int bb = m0 >> 11;
        int s_base = (m0 & (SEQ - 1)) + wm;
        int dd = lane >> 2;
        int ss = (lane & 3) * 8;
        size_t obase = ((size_t)(bb * NH + h) * HD) * SEQ;
#pragma unroll
        for (int half = 0; half < 2; half++) {
#pragma unroll
            for (int mh = 0; mh < 2; mh++) {
                int mf = half * 2 + mh;
#pragma unroll
                for (int nf = 0; nf < 4; nf++) {
                    int col = n0 + wn + nf * 16 + c;
                    int d = nf * 16 + c;
                    float bval = bias[col];
                    bf16x4 pk;
#pragma unroll
                    for (int r = 0; r < 4; r++) pk[r] = (__bf16)(acc[mf][nf][r] + bval);
                    *(bf16x4*)&T[d * 36 + mh * 16 + g * 4] = pk;
                }
            }
#pragma unroll
            for (int dgrp = 0; dgrp < 4; dgrp++) {
                int d = dgrp * 16 + dd;
                bf16x8 vv = *(bf16x8*)&T[d * 36 + ss];
                *(bf16x8*)&ovT[obase + (size_t)d * SEQ + s_base + half * 32 + ss] = vv;
            }
        }
    } else {
        __bf16* Out = (z == 0) ? oq : ok;
#pragma unroll
        for (int nf = 0; nf < 4; nf++) {
            int col = n0 + wn + nf * 16 + c;
            float bval = bias[col];
#pragma unroll
            for (int mf = 0; mf < 4; mf++) {
                int row = m0 + wm + mf * 16 + g * 4;
#pragma unroll
                for (int r = 0; r < 4; r++)
                    Out[(size_t)(row + r) * DIM + col] = (__bf16)(acc[mf][nf][r] + bval);
            }
        }
    }
}

// ---------------------------------------------------------------------------
// Kernel 2 (fallback, small ws): fp32-A projection GEMM (round-6 form).
// ---------------------------------------------------------------------------
__global__ __launch_bounds__(256, 2) void gemm_proj_f32(
    const float* __restrict__ Xq, const float* __restrict__ Xk,
    const float* __restrict__ Xv, const __bf16* __restrict__ wt,
    const float* __restrict__ bq, const float* __restrict__ bk,
    const float* __restrict__ bv,
    __bf16* __restrict__ oq, __bf16* __restrict__ ok, __bf16* __restrict__ ovT)
{
    int z = blockIdx.z;
    const float*  X    = (z == 0) ? Xq : (z == 1) ? Xk : Xv;
    const float*  bias = (z == 0) ? bq : (z == 1) ? bk : bv;
    const __bf16* Bt   = wt + (size_t)z * DIM * DIM;

    __shared__ __align__(16) char smem[36864];
    __bf16* const Ab = (__bf16*)smem;
    __bf16* const Bb = (__bf16*)(smem + 16384);

    int m0 = blockIdx.x * 128, n0 = blockIdx.y * 128;
    int tid = threadIdx.x, lane = tid & 63, w = tid >> 6;
    int c = lane & 15, g = lane >> 4;
    int wm = (w >> 1) * 64, wn = (w & 1) * 64;

    f32x4 acc[4][4] = {};

    int ar = tid >> 1, ah = tid & 1;
    const float* aptr = X + (size_t)(m0 + ar) * DIM + ah * 16;
    int awo = ar * 32 + ah * 16;

    int brow0 = (w * 2) * 16 + (lane >> 2);
    int bcol  = (lane & 3) * 8;
    const __bf16* bptr0 = Bt + (size_t)(n0 + brow0) * DIM + bcol;
    const __bf16* bptr1 = bptr0 + (size_t)16 * DIM;
    int bwo0 = (w * 2) * 512;
    int bwo1 = (w * 2 + 1) * 512;

    {
        f32x4 f0 = *(const f32x4*)(aptr);
        f32x4 f1 = *(const f32x4*)(aptr + 4);
        f32x4 f2 = *(const f32x4*)(aptr + 8);
        f32x4 f3 = *(const f32x4*)(aptr + 12);
        GLD_LDS16(bptr0, Bb + bwo0);
        GLD_LDS16(bptr1, Bb + bwo1);
        bf16x8 b0, b1;
#pragma unroll
        for (int j = 0; j < 4; j++) {
            b0[j] = (__bf16)f0[j]; b0[4 + j] = (__bf16)f1[j];
            b1[j] = (__bf16)f2[j]; b1[4 + j] = (__bf16)f3[j];
        }
        *(bf16x8*)(Ab + awo)     = b0;
        *(bf16x8*)(Ab + awo + 8) = b1;
    }
    __syncthreads();

    int cur = 0;
    for (int kt = 0; kt < 32; ++kt) {
        int nxt = kt + 1;
        int nb = cur ^ 1;
        f32x4 f0, f1, f2, f3;
        if (nxt < 32) {
            const float* ap = aptr + nxt * 32;
            f0 = *(const f32x4*)(ap);
            f1 = *(const f32x4*)(ap + 4);
            f2 = *(const f32x4*)(ap + 8);
            f3 = *(const f32x4*)(ap + 12);
            GLD_LDS16(bptr0 + nxt * 32, Bb + nb * 4096 + bwo0);
            GLD_LDS16(bptr1 + nxt * 32, Bb + nb * 4096 + bwo1);
        }
        bf16x8 af[4], bf[4];
#pragma unroll
        for (int mf = 0; mf < 4; mf++)
            af[mf] = *(bf16x8*)&Ab[cur * 4096 + (wm + mf * 16 + c) * 32 + g * 8];
#pragma unroll
        for (int nf = 0; nf < 4; nf++)
            bf[nf] = *(bf16x8*)&Bb[cur * 4096 + (wn + nf * 16 + c) * 32 + g * 8];
#pragma unroll
        for (int mf = 0; mf < 4; mf++)
#pragma unroll
            for (int nf = 0; nf < 4; nf++)
                acc[mf][nf] = mfma16(af[mf], bf[nf], acc[mf][nf]);
        if (nxt < 32) {
            bf16x8 b0, b1;
#pragma unroll
            for (int j = 0; j < 4; j++) {
                b0[j] = (__bf16)f0[j]; b0[4 + j] = (__bf16)f1[j];
                b1[j] = (__bf16)f2[j]; b1[4 + j] = (__bf16)f3[j];
            }
            *(bf16x8*)(Ab + nb * 4096 + awo)     = b0;
            *(bf16x8*)(Ab + nb * 4096 + awo + 8) = b1;
        }
        __syncthreads();
        cur = nb;
    }

    if (z == 2) {
        __bf16* T = (__bf16*)smem + (size_t)w * 4608;
#pragma unroll
        for (int nf = 0; nf < 4; nf++) {
            int col = n0 + wn + nf * 16 + c;
            int d = nf * 16 + c;
            float bval = bias[col];
#pragma unroll
            for (int mf = 0; mf < 4; mf++) {
                int sl = mf * 16 + g * 4;
                bf16x4 pk;
#pragma unroll
                for (int r = 0; r < 4; r++) pk[r] = (__bf16)(acc[mf][nf][r] + bval);
                *(bf16x4*)&T[d * 72 + sl] = pk;
            }
        }
        int h = (n0 + wn) >> 6;
        int bb = m0 >> 11;
        int s_base = (m0 & (SEQ - 1)) + wm;
        int dd = lane >> 2;
        int ss = (lane & 3) * 8;
        size_t obase = ((size_t)(bb * NH + h) * HD) * SEQ;
#pragma unroll
        for (int dgrp = 0; dgrp < 4; dgrp++)
#pragma unroll
            for (int half = 0; half < 2; half++) {
                int d = dgrp * 16 + dd;
                int s = half * 32 + ss;
                bf16x8 vv = *(bf16x8*)&T[d * 72 + s];
                *(bf16x8*)&ovT[obase + (size_t)d * SEQ + s_base + s] = vv;
            }
    } else {
        __bf16* Out = (z == 0) ? oq : ok;
#pragma unroll
        for (int nf = 0; nf < 4; nf++) {
            int col = n0 + wn + nf * 16 + c;
            float bval = bias[col];
#pragma unroll
            for (int mf = 0; mf < 4; mf++) {
                int row = m0 + wm + mf * 16 + g * 4;
#pragma unroll
                for (int r = 0; r < 4; r++)
                    Out[(size_t)(row + r) * DIM + col] = (__bf16)(acc[mf][nf][r] + bval);
            }
        }
    }
}

// ---------------------------------------------------------------------------
// Kernel 3: causal flash attention, swapped-operand, KVBLK=128 (round-11).
// ---------------------------------------------------------------------------
#define QSCALE 0.180336880f   // 0.125 * log2(e); softmax in exp2 domain

__global__ __launch_bounds__(256, 2) void fa_kernel(
    const __bf16* __restrict__ qp, const __bf16* __restrict__ kp,
    const __bf16* __restrict__ vpT, __bf16* __restrict__ op)
{
    int bz = blockIdx.x;
    int bh = bz & 63;
    int b = bh >> 4, h = bh & 15;
    int qt = 31 - (bz >> 6);          // heaviest tiles first
    int q0 = qt * 64;

    int tid = threadIdx.x, lane = tid & 63, w = tid >> 6;
    int c = lane & 15, g = lane >> 4;

    __shared__ __bf16 Kbuf[128 * 64];   // [key][d] 16KB
    __shared__ __bf16 Vbuf[64 * 128];   // [d][key] 16KB

    const int qg = q0 + w * 16 + c;

    bf16x8 qf[2];
    {
        const __bf16* qbase = qp + (size_t)(b * SEQ + qg) * DIM + h * HD;
#pragma unroll
        for (int kc = 0; kc < 2; kc++) {
            bf16x8 raw = *(const bf16x8*)(qbase + kc * 32 + g * 8);
            bf16x8 sc;
#pragma unroll
            for (int j = 0; j < 8; j++) sc[j] = (__bf16)((float)raw[j] * QSCALE);
            qf[kc] = sc;
        }
    }

    f32x4 acc[4] = {};
    float m_run = -1e30f;
    float l_run = 0.f;

    int kr = tid >> 3, kch = tid & 7;
    int ksch = kch ^ (kr & 7);
    const __bf16* kbase = kp + (size_t)(b * SEQ + kr) * DIM + h * HD + ksch * 8;
    int vr = tid >> 4, vch = tid & 15;
    int vsch = vch ^ (vr & 7);
    const __bf16* vbase = vpT + ((size_t)(b * NH + h) * HD + vr) * SEQ + vsch * 8;

    int vb4[8];
#pragma unroll
    for (int mkey = 0; mkey < 8; mkey++)
        vb4[mkey] = c * 128 + (((2 * mkey + (g >> 1)) ^ (c & 7)) * 8) + (g & 1) * 4;

    int ktmax = (qt >> 1) + 1;
    for (int kt = 0; kt < ktmax; ++kt) {
        const __bf16* kln = kbase + (size_t)kt * 128 * DIM;
        const __bf16* vln = vbase + kt * 128;
        GLD_LDS16(kln,                       Kbuf + w * 512);
        GLD_LDS16(kln + (size_t)32 * DIM,    Kbuf + 2048 + w * 512);
        GLD_LDS16(kln + (size_t)64 * DIM,    Kbuf + 4096 + w * 512);
        GLD_LDS16(kln + (size_t)96 * DIM,    Kbuf + 6144 + w * 512);
        GLD_LDS16(vln,                       Vbuf + w * 512);
        GLD_LDS16(vln + (size_t)16 * SEQ,    Vbuf + 2048 + w * 512);
        GLD_LDS16(vln + (size_t)32 * SEQ,    Vbuf + 4096 + w * 512);
        GLD_LDS16(vln + (size_t)48 * SEQ,    Vbuf + 6144 + w * 512);
        __syncthreads();

        int kb0 = kt * 128;

        // ---- S^T = K Q^T (16 MFMA; kf chunked to limit liveness) ----
        f32x4 s[8] = {};
        __builtin_amdgcn_s_setprio(1);
#pragma unroll
        for (int kc = 0; kc < 2; kc++) {
#pragma unroll
            for (int mh = 0; mh < 2; mh++) {
                bf16x8 kf[4];
#pragma unroll
                for (int mq = 0; mq < 4; mq++)
                    kf[mq] = *(bf16x8*)&Kbuf[((mh * 4 + mq) * 16 + c) * 64 + (((kc * 4 + g) ^ (c & 7)) * 8)];
#pragma unroll
                for (int mq = 0; mq < 4; mq++)
                    s[mh * 4 + mq] = mfma16(kf[mq], qf[kc], s[mh * 4 + mq]);
            }
        }
        __builtin_amdgcn_s_setprio(0);

        // ---- causal mask (boundary region only) ----
        if (kb0 + 127 > qg) {
#pragma unroll
            for (int mkey = 0; mkey < 8; mkey++)
#pragma unroll
                for (int r2 = 0; r2 < 4; r2++)
                    if (kb0 + mkey * 16 + g * 4 + r2 > qg) s[mkey][r2] = -1e30f;
        }

        // ---- ONE softmax pass per 128 keys: defer-max, bare exp2 ----
        float fm0 = fmaxf(fmaxf(s[0][0], s[0][1]), fmaxf(s[0][2], s[0][3]));
        float fm1 = fmaxf(fmaxf(s[1][0], s[1][1]), fmaxf(s[1][2], s[1][3]));
        float fm2 = fmaxf(fmaxf(s[2][0], s[2][1]), fmaxf(s[2][2], s[2][3]));
        float fm3 = fmaxf(fmaxf(s[3][0], s[3][1]), fmaxf(s[3][2], s[3][3]));
        float fm4 = fmaxf(fmaxf(s[4][0], s[4][1]), fmaxf(s[4][2], s[4][3]));
        float fm5 = fmaxf(fmaxf(s[5][0], s[5][1]), fmaxf(s[5][2], s[5][3]));
        float fm6 = fmaxf(fmaxf(s[6][0], s[6][1]), fmaxf(s[6][2], s[6][3]));
        float fm7 = fmaxf(fmaxf(s[7][0], s[7][1]), fmaxf(s[7][2], s[7][3]));
        float pm = fmaxf(fmaxf(fmaxf(fm0, fm1), fmaxf(fm2, fm3)),
                         fmaxf(fmaxf(fm4, fm5), fmaxf(fm6, fm7)));
        pm = fmaxf(pm, __shfl_xor(pm, 16));
        pm = fmaxf(pm, __shfl_xor(pm, 32));
        if (!__all(pm <= m_run + 8.f)) {
            float mn = fmaxf(m_run, pm);
            float scl = fast_exp2(m_run - mn);
            l_run *= scl;
#pragma unroll
            for (int nf = 0; nf < 4; nf++) acc[nf] *= scl;
            m_run = mn;
        }
        f32x4 rsv = {0.f, 0.f, 0.f, 0.f};
        bf16x4 pf[8];
#pragma unroll
        for (int mkey = 0; mkey < 8; mkey++) {
            bf16x4 pk;
#pragma unroll
            for (int r2 = 0; r2 < 4; r2++) {
                float p = fast_exp2(s[mkey][r2] - m_run);
                rsv[r2] += p;
                pk[r2] = (__bf16)p;
            }
            pf[mkey] = pk;
        }
        float rs = (rsv[0] + rsv[1]) + (rsv[2] + rsv[3]);
        rs += __shfl_xor(rs, 16);
        rs += __shfl_xor(rs, 32);
        l_run += rs;

        // ---- O^T += V^T P^T (32 k16-MFMA) ----
        __builtin_amdgcn_s_setprio(1);
#pragma unroll
        for (int mkey = 0; mkey < 8; mkey++) {
#pragma unroll
            for (int nf = 0; nf < 4; nf++) {
                bf16x4 vf = *(bf16x4*)&Vbuf[vb4[mkey] + nf * 2048];
                acc[nf] = mfma16k16(vf, pf[mkey], acc[nf]);
            }
        }
        __builtin_amdgcn_s_setprio(0);
        __syncthreads();
    }

    // ---- epilogue ----
    {
        float inv = 1.f / l_run;
        __bf16* obase = op + (size_t)(b * SEQ + qg) * DIM + h * HD + g * 4;
#pragma unroll
        for (int nf = 0; nf < 4; nf++) {
            bf16x4 pk;
#pragma unroll
            for (int r2 = 0; r2 < 4; r2++) pk[r2] = (__bf16)(acc[nf][r2] * inv);
            *(bf16x4*)(obase + nf * 16) = pk;
        }
    }
}

// ---------------------------------------------------------------------------
// Kernel 4: output GEMM, dbuf pipeline.
// ---------------------------------------------------------------------------
__global__ __launch_bounds__(256, 2) void gemm_out(
    const __bf16* __restrict__ Ain, const __bf16* __restrict__ wt,
    const float* __restrict__ bias, float* __restrict__ Out)
{
    const __bf16* Bt = wt + (size_t)3 * DIM * DIM;

    __shared__ __bf16 Ab[2][4096];
    __shared__ __bf16 Bb[2][4096];

    int m0 = blockIdx.x * 128, n0 = blockIdx.y * 128;
    int tid = threadIdx.x, lane = tid & 63, w = tid >> 6;
    int c = lane & 15, g = lane >> 4;
    int wm = (w >> 1) * 64, wn = (w & 1) * 64;

    f32x4 acc[4][4] = {};

    int srow = (w * 2) * 16 + (lane >> 2);
    int scol = (lane & 3) * 8;
    const __bf16* aptr0 = Ain + (size_t)(m0 + srow) * DIM + scol;
    const __bf16* aptr1 = aptr0 + (size_t)16 * DIM;
    const __bf16* bptr0 = Bt + (size_t)(n0 + srow) * DIM + scol;
    const __bf16* bptr1 = bptr0 + (size_t)16 * DIM;
    int so0 = (w * 2) * 512;
    int so1 = (w * 2 + 1) * 512;

    GLD_LDS16(aptr0, Ab[0] + so0);
    GLD_LDS16(aptr1, Ab[0] + so1);
    GLD_LDS16(bptr0, Bb[0] + so0);
    GLD_LDS16(bptr1, Bb[0] + so1);
    __syncthreads();

    int cur = 0;
    for (int kt = 0; kt < 32; ++kt) {
        int nxt = kt + 1;
        int nb = cur ^ 1;
        if (nxt < 32) {
            int k0 = nxt * 32;
            GLD_LDS16(aptr0 + k0, Ab[nb] + so0);
            GLD_LDS16(aptr1 + k0, Ab[nb] + so1);
            GLD_LDS16(bptr0 + k0, Bb[nb] + so0);
            GLD_LDS16(bptr1 + k0, Bb[nb] + so1);
        }
        bf16x8 af[4], bf[4];
#pragma unroll
        for (int mf = 0; mf < 4; mf++)
            af[mf] = *(bf16x8*)&Ab[cur][(wm + mf * 16 + c) * 32 + g * 8];
#pragma unroll
        for (int nf = 0; nf < 4; nf++)
            bf[nf] = *(bf16x8*)&Bb[cur][(wn + nf * 16 + c) * 32 + g * 8];
#pragma unroll
        for (int mf = 0; mf < 4; mf++)
#pragma unroll
            for (int nf = 0; nf < 4; nf++)
                acc[mf][nf] = mfma16(af[mf], bf[nf], acc[mf][nf]);
        __syncthreads();
        cur = nb;
    }

#pragma unroll
    for (int nf = 0; nf < 4; nf++) {
        int col = n0 + wn + nf * 16 + c;
        float bval = bias[col];
#pragma unroll
        for (int mf = 0; mf < 4; mf++) {
            int row = m0 + wm + mf * 16 + g * 4;
#pragma unroll
            for (int r = 0; r < 4; r++)
                Out[(size_t)(row + r) * DIM + col] = acc[mf][nf][r] + bval;
        }
    }
}

// ---------------------------------------------------------------------------
extern "C" void kernel_launch(void* const* d_in, const int* in_sizes, int n_in,
                              void* d_out, int out_size, void* d_ws, size_t ws_size,
                              hipStream_t stream)
{
    const float* q  = (const float*)d_in[0];
    const float* k  = (const float*)d_in[1];
    const float* v  = (const float*)d_in[2];
    // d_in[3] = mask (known causal; applied analytically)
    const float* Wq = (const float*)d_in[4];
    const float* bq = (const float*)d_in[5];
    const float* Wk = (const float*)d_in[6];
    const float* bk = (const float*)d_in[7];
    const float* Wv = (const float*)d_in[8];
    const float* bv = (const float*)d_in[9];
    const float* Wo = (const float*)d_in[10];
    const float* bo = (const float*)d_in[11];

    char* ws = (char*)d_ws;
    __bf16* wt  = (__bf16*)ws;                             // 8 MB (4 x 2MB)
    __bf16* qp  = (__bf16*)(ws + (size_t)(8u  << 20));     // 16 MB
    __bf16* kp  = (__bf16*)(ws + (size_t)(24u << 20));     // 16 MB
    __bf16* vpT = (__bf16*)(ws + (size_t)(40u << 20));     // 16 MB
    __bf16* ao  = (__bf16*)(ws + (size_t)(56u << 20));     // 16 MB
    __bf16* xq  = (__bf16*)(ws + (size_t)(72u << 20));     // 16 MB
    __bf16* xk  = (__bf16*)(ws + (size_t)(88u << 20));     // 16 MB
    __bf16* xv  = (__bf16*)(ws + (size_t)(104u << 20));    // 16 MB (end: 120MB)

    wt_kernel<<<dim3(16, 16, 4), 256, 0, stream>>>(Wq, Wk, Wv, Wo, wt);
    if (ws_size >= ((size_t)120u << 20)) {
        cvt_kernel<<<dim3(4096, 3), 256, 0, stream>>>(q, k, v, xq, xk, xv);
        gemm_proj<<<dim3(64, 8, 3), 256, 0, stream>>>(xq, xk, xv, wt, bq, bk, bv, qp, kp, vpT);
    } else {
        gemm_proj_f32<<<dim3(64, 8, 3), 256, 0, stream>>>(q, k, v, wt, bq, bk, bv, qp, kp, vpT);
    }
    fa_kernel<<<dim3(2048), 256, 0, stream>>>(qp, kp, vpT, ao);
    gemm_out<<<dim3(64, 8), 256, 0, stream>>>(ao, wt, bo, (float*)d_out);

    (void)in_sizes; (void)n_in; (void)out_size;
}

// Round 13
// 171.719 us; speedup vs baseline: 1.1157x; 1.1157x over previous
//
#include <hip/hip_runtime.h>

#define Bsz 4
#define SEQ 2048
#define DIM 1024
#define NH 16
#define HD 64

typedef float  f32x4  __attribute__((ext_vector_type(4)));
typedef __bf16 bf16x8 __attribute__((ext_vector_type(8)));
typedef __bf16 bf16x4 __attribute__((ext_vector_type(4)));
typedef short  s16x4  __attribute__((ext_vector_type(4)));

__device__ __forceinline__ f32x4 mfma16(bf16x8 a, bf16x8 b, f32x4 c) {
    return __builtin_amdgcn_mfma_f32_16x16x32_bf16(a, b, c, 0, 0, 0);
}
__device__ __forceinline__ f32x4 mfma16k16(bf16x4 a, bf16x4 b, f32x4 c) {
#if defined(__has_builtin) && __has_builtin(__builtin_amdgcn_mfma_f32_16x16x16bf16_1k)
    return __builtin_amdgcn_mfma_f32_16x16x16bf16_1k(
        __builtin_bit_cast(s16x4, a), __builtin_bit_cast(s16x4, b), c, 0, 0, 0);
#else
    asm volatile("s_nop 2\n\tv_mfma_f32_16x16x16_bf16 %0, %1, %2, %0\n\ts_nop 7\n\ts_nop 7"
                 : "+v"(c) : "v"(a), "v"(b));
    return c;
#endif
}

// bare HW exp2 (single v_exp_f32)
__device__ __forceinline__ float fast_exp2(float x) {
#if defined(__has_builtin) && __has_builtin(__builtin_amdgcn_exp2f)
    return __builtin_amdgcn_exp2f(x);
#else
    return exp2f(x);
#endif
}

#define GLD_LDS16(gsrc, ldst)                                                        \
    __builtin_amdgcn_global_load_lds(                                                \
        (const __attribute__((address_space(1))) void*)(gsrc),                       \
        (__attribute__((address_space(3))) void*)(ldst), 16, 0, 0)

// ---------------------------------------------------------------------------
// Kernel 1: transpose + convert weights fp32 [K][N] -> bf16 Wt [N][K]
// ---------------------------------------------------------------------------
__global__ __launch_bounds__(256) void wt_kernel(
    const float* __restrict__ Wq, const float* __restrict__ Wk,
    const float* __restrict__ Wv, const float* __restrict__ Wo,
    __bf16* __restrict__ wt)
{
    __shared__ float tile[64][65];
    int z = blockIdx.z;
    const float* W = (z == 0) ? Wq : (z == 1) ? Wk : (z == 2) ? Wv : Wo;
    __bf16* out = wt + (size_t)z * DIM * DIM;
    int kb = blockIdx.x * 64, nb = blockIdx.y * 64;
    int t = threadIdx.x;
    int cidx = t & 63, ridx = t >> 6;
#pragma unroll
    for (int i = 0; i < 16; i++) {
        int r = ridx + i * 4;
        tile[r][cidx] = W[(size_t)(kb + r) * DIM + nb + cidx];
    }
    __syncthreads();
#pragma unroll
    for (int i = 0; i < 16; i++) {
        int r = ridx + i * 4;
        out[(size_t)(nb + r) * DIM + kb + cidx] = (__bf16)tile[cidx][r];
    }
}

// ---------------------------------------------------------------------------
// Kernel 2: projection GEMM (r11 winner): fp32-A staged DIRECTLY into LDS
// via global_load_lds; A reads XOR-chunk swizzled; cvt at MFMA-feed.
// dbuf, 1 barrier/K-step. z=2 (V): transposed-per-head store via LDS tile.
// ---------------------------------------------------------------------------
__global__ __launch_bounds__(256, 2) void gemm_proj(
    const float* __restrict__ Xq, const float* __restrict__ Xk,
    const float* __restrict__ Xv, const __bf16* __restrict__ wt,
    const float* __restrict__ bq, const float* __restrict__ bk,
    const float* __restrict__ bv,
    __bf16* __restrict__ oq, __bf16* __restrict__ ok, __bf16* __restrict__ ovT)
{
    int z = blockIdx.z;
    const float*  X    = (z == 0) ? Xq : (z == 1) ? Xk : Xv;
    const float*  bias = (z == 0) ? bq : (z == 1) ? bk : bv;
    const __bf16* Bt   = wt + (size_t)z * DIM * DIM;

    __shared__ __align__(16) char smem[49152];      // A f32 2x16KB + B bf16 2x8KB
    float*  const Af = (float*)smem;                // [2][4096] floats
    __bf16* const Bb = (__bf16*)(smem + 32768);     // [2][4096] bf16

    int m0 = blockIdx.x * 128, n0 = blockIdx.y * 128;
    int tid = threadIdx.x, lane = tid & 63, w = tid >> 6;
    int c = lane & 15, g = lane >> 4;
    int wm = (w >> 1) * 64, wn = (w & 1) * 64;

    f32x4 acc[4][4] = {};

    int ar = tid >> 3, ach = tid & 7;
    int asch = ach ^ (ar & 7);
    const float* aptr = X + (size_t)(m0 + ar) * DIM + asch * 4;
    int srow = (w * 2) * 16 + (lane >> 2);
    int scol = (lane & 3) * 8;
    const __bf16* bptr0 = Bt + (size_t)(n0 + srow) * DIM + scol;
    const __bf16* bptr1 = bptr0 + (size_t)16 * DIM;
    int so0 = (w * 2) * 512;
    int so1 = (w * 2 + 1) * 512;

#define STAGE_PROJ(buf, k0)                                                      \
    do {                                                                         \
        GLD_LDS16(aptr + (k0),                     Af + (buf) * 4096 + w * 256); \
        GLD_LDS16(aptr + (k0) + (size_t)32 * DIM,  Af + (buf) * 4096 + 1024 + w * 256); \
        GLD_LDS16(aptr + (k0) + (size_t)64 * DIM,  Af + (buf) * 4096 + 2048 + w * 256); \
        GLD_LDS16(aptr + (k0) + (size_t)96 * DIM,  Af + (buf) * 4096 + 3072 + w * 256); \
        GLD_LDS16(bptr0 + (k0),                    Bb + (buf) * 4096 + so0);     \
        GLD_LDS16(bptr1 + (k0),                    Bb + (buf) * 4096 + so1);     \
    } while (0)

    STAGE_PROJ(0, 0);
    __syncthreads();

    int cur = 0;
    for (int kt = 0; kt < 32; ++kt) {
        int nxt = kt + 1;
        int nb = cur ^ 1;
        if (nxt < 32) STAGE_PROJ(nb, nxt * 32);

        bf16x8 af[4], bf[4];
#pragma unroll
        for (int mf = 0; mf < 4; mf++) {
            int arow = wm + mf * 16 + c;
            const float* ap = &Af[cur * 4096 + arow * 32];
            f32x4 a0 = *(const f32x4*)(ap + (((2 * g)     ^ (c & 7)) << 2));
            f32x4 a1 = *(const f32x4*)(ap + (((2 * g + 1) ^ (c & 7)) << 2));
            bf16x8 v;
#pragma unroll
            for (int j = 0; j < 4; j++) { v[j] = (__bf16)a0[j]; v[4 + j] = (__bf16)a1[j]; }
            af[mf] = v;
        }
#pragma unroll
        for (int nf = 0; nf < 4; nf++)
            bf[nf] = *(bf16x8*)&Bb[cur * 4096 + (wn + nf * 16 + c) * 32 + g * 8];
#pragma unroll
        for (int mf = 0; mf < 4; mf++)
#pragma unroll
            for (int nf = 0; nf < 4; nf++)
                acc[mf][nf] = mfma16(af[mf], bf[nf], acc[mf][nf]);
        __syncthreads();
        cur = nb;
    }
#undef STAGE_PROJ

    if (z == 2) {
        __bf16* T = (__bf16*)smem + (size_t)w * 2304;   // 64 x 36 elems/wave
        int h = (n0 + wn) >> 6;
        int bb = m0 >> 11;
        int s_base = (m0 & (SEQ - 1)) + wm;
        int dd = lane >> 2;
        int ss = (lane & 3) * 8;
        size_t obase = ((size_t)(bb * NH + h) * HD) * SEQ;
#pragma unroll
        for (int half = 0; half < 2; half++) {
#pragma unroll
            for (int mh = 0; mh < 2; mh++) {
                int mf = half * 2 + mh;
#pragma unroll
                for (int nf = 0; nf < 4; nf++) {
                    int col = n0 + wn + nf * 16 + c;
                    int d = nf * 16 + c;
                    float bval = bias[col];
                    bf16x4 pk;
#pragma unroll
                    for (int r = 0; r < 4; r++) pk[r] = (__bf16)(acc[mf][nf][r] + bval);
                    *(bf16x4*)&T[d * 36 + mh * 16 + g * 4] = pk;
                }
            }
#pragma unroll
            for (int dgrp = 0; dgrp < 4; dgrp++) {
                int d = dgrp * 16 + dd;
                bf16x8 vv = *(bf16x8*)&T[d * 36 + ss];
                *(bf16x8*)&ovT[obase + (size_t)d * SEQ + s_base + half * 32 + ss] = vv;
            }
        }
    } else {
        __bf16* Out = (z == 0) ? oq : ok;
#pragma unroll
        for (int nf = 0; nf < 4; nf++) {
            int col = n0 + wn + nf * 16 + c;
            float bval = bias[col];
#pragma unroll
            for (int mf = 0; mf < 4; mf++) {
                int row = m0 + wm + mf * 16 + g * 4;
#pragma unroll
                for (int r = 0; r < 4; r++)
                    Out[(size_t)(row + r) * DIM + col] = (__bf16)(acc[mf][nf][r] + bval);
            }
        }
    }
}

// ---------------------------------------------------------------------------
// Kernel 3: causal flash attention (r10 winner): swapped-operand, KVBLK=64,
// SINGLE-buffered 16KB LDS (occ 53%), 64 Q-rows/block, defer-max,
// bare exp2, setprio around MFMA clusters.
// ---------------------------------------------------------------------------
#define QSCALE 0.180336880f   // 0.125 * log2(e); softmax in exp2 domain

__global__ __launch_bounds__(256, 2) void fa_kernel(
    const __bf16* __restrict__ qp, const __bf16* __restrict__ kp,
    const __bf16* __restrict__ vpT, __bf16* __restrict__ op)
{
    int bz = blockIdx.x;
    int bh = bz & 63;
    int b = bh >> 4, h = bh & 15;
    int qt = 31 - (bz >> 6);          // heaviest tiles first
    int q0 = qt * 64;

    int tid = threadIdx.x, lane = tid & 63, w = tid >> 6;
    int c = lane & 15, g = lane >> 4;

    __shared__ __bf16 Kbuf[64 * 64];
    __shared__ __bf16 Vbuf[64 * 64];

    const int qg = q0 + w * 16 + c;

    bf16x8 qf[2];
    {
        const __bf16* qbase = qp + (size_t)(b * SEQ + qg) * DIM + h * HD;
#pragma unroll
        for (int kc = 0; kc < 2; kc++) {
            bf16x8 raw = *(const bf16x8*)(qbase + kc * 32 + g * 8);
            bf16x8 sc;
#pragma unroll
            for (int j = 0; j < 8; j++) sc[j] = (__bf16)((float)raw[j] * QSCALE);
            qf[kc] = sc;
        }
    }

    f32x4 acc[4] = {};
    float m_run = -1e30f;
    float l_run = 0.f;

    int r8 = tid >> 3, c8 = tid & 7;
    int sch = c8 ^ (r8 & 7);
    const __bf16* kbase = kp  + (size_t)(b * SEQ + r8) * DIM + h * HD + sch * 8;
    const __bf16* vbase = vpT + ((size_t)(b * NH + h) * HD + r8) * SEQ + sch * 8;
    __bf16* kdst0 = Kbuf + w * 512;
    __bf16* kdst1 = Kbuf + 2048 + w * 512;
    __bf16* vdst0 = Vbuf + w * 512;
    __bf16* vdst1 = Vbuf + 2048 + w * 512;

    int vb4[4];
#pragma unroll
    for (int mkey = 0; mkey < 4; mkey++)
        vb4[mkey] = c * 64 + (((2 * mkey + (g >> 1)) ^ (c & 7)) * 8) + (g & 1) * 4;

    int ktmax = qt + 1;
    for (int kt = 0; kt < ktmax; ++kt) {
        GLD_LDS16(kbase + (size_t)kt * 64 * DIM, kdst0);
        GLD_LDS16(kbase + (size_t)(kt * 64 + 32) * DIM, kdst1);
        GLD_LDS16(vbase + kt * 64, vdst0);
        GLD_LDS16(vbase + kt * 64 + (size_t)32 * SEQ, vdst1);
        __syncthreads();

        int kb0 = kt * 64;

        // ---- S^T = K Q^T ----
        f32x4 s[4] = {};
        __builtin_amdgcn_s_setprio(1);
#pragma unroll
        for (int kc = 0; kc < 2; kc++) {
            bf16x8 kf[4];
#pragma unroll
            for (int mkey = 0; mkey < 4; mkey++)
                kf[mkey] = *(bf16x8*)&Kbuf[(mkey * 16 + c) * 64 + (((kc * 4 + g) ^ (c & 7)) * 8)];
#pragma unroll
            for (int mkey = 0; mkey < 4; mkey++)
                s[mkey] = mfma16(kf[mkey], qf[kc], s[mkey]);
        }
        __builtin_amdgcn_s_setprio(0);

        // ---- causal mask (boundary tile only) ----
        if (kb0 + 63 > qg) {
#pragma unroll
            for (int mkey = 0; mkey < 4; mkey++)
#pragma unroll
                for (int r2 = 0; r2 < 4; r2++)
                    if (kb0 + mkey * 16 + g * 4 + r2 > qg) s[mkey][r2] = -1e30f;
        }

        // ---- online softmax: defer-max, max3 chain, bare exp2 ----
        float pm = fmaxf(fmaxf(s[0][0], s[0][1]), s[0][2]);
        pm = fmaxf(fmaxf(pm, s[0][3]), s[1][0]);
        pm = fmaxf(fmaxf(pm, s[1][1]), s[1][2]);
        pm = fmaxf(fmaxf(pm, s[1][3]), s[2][0]);
        pm = fmaxf(fmaxf(pm, s[2][1]), s[2][2]);
        pm = fmaxf(fmaxf(pm, s[2][3]), s[3][0]);
        pm = fmaxf(fmaxf(pm, s[3][1]), s[3][2]);
        pm = fmaxf(pm, s[3][3]);
        pm = fmaxf(pm, __shfl_xor(pm, 16));
        pm = fmaxf(pm, __shfl_xor(pm, 32));
        if (!__all(pm <= m_run + 8.f)) {
            float mn = fmaxf(m_run, pm);
            float scl = fast_exp2(m_run - mn);
            l_run *= scl;
#pragma unroll
            for (int nf = 0; nf < 4; nf++) acc[nf] *= scl;
            m_run = mn;
        }
        f32x4 rsv = {0.f, 0.f, 0.f, 0.f};
        bf16x4 pf[4];
#pragma unroll
        for (int mkey = 0; mkey < 4; mkey++) {
            bf16x4 pk;
#pragma unroll
            for (int r2 = 0; r2 < 4; r2++) {
                float p = fast_exp2(s[mkey][r2] - m_run);
                rsv[r2] += p;
                pk[r2] = (__bf16)p;
            }
            pf[mkey] = pk;
        }
        float rs = (rsv[0] + rsv[1]) + (rsv[2] + rsv[3]);
        rs += __shfl_xor(rs, 16);
        rs += __shfl_xor(rs, 32);
        l_run += rs;

        // ---- O^T += V^T P^T ----
        __builtin_amdgcn_s_setprio(1);
#pragma unroll
        for (int mkey = 0; mkey < 4; mkey++) {
#pragma unroll
            for (int nf = 0; nf < 4; nf++) {
                bf16x4 vf = *(bf16x4*)&Vbuf[vb4[mkey] + nf * 1024];
                acc[nf] = mfma16k16(vf, pf[mkey], acc[nf]);
            }
        }
        __builtin_amdgcn_s_setprio(0);
        __syncthreads();
    }

    // ---- epilogue ----
    {
        float inv = 1.f / l_run;
        __bf16* obase = op + (size_t)(b * SEQ + qg) * DIM + h * HD + g * 4;
#pragma unroll
        for (int nf = 0; nf < 4; nf++) {
            bf16x4 pk;
#pragma unroll
            for (int r2 = 0; r2 < 4; r2++) pk[r2] = (__bf16)(acc[nf][r2] * inv);
            *(bf16x4*)(obase + nf * 16) = pk;
        }
    }
}

// ---------------------------------------------------------------------------
// Kernel 4: output GEMM, dbuf pipeline.
// ---------------------------------------------------------------------------
__global__ __launch_bounds__(256, 2) void gemm_out(
    const __bf16* __restrict__ Ain, const __bf16* __restrict__ wt,
    const float* __restrict__ bias, float* __restrict__ Out)
{
    const __bf16* Bt = wt + (size_t)3 * DIM * DIM;

    __shared__ __bf16 Ab[2][4096];
    __shared__ __bf16 Bb[2][4096];

    int m0 = blockIdx.x * 128, n0 = blockIdx.y * 128;
    int tid = threadIdx.x, lane = tid & 63, w = tid >> 6;
    int c = lane & 15, g = lane >> 4;
    int wm = (w >> 1) * 64, wn = (w & 1) * 64;

    f32x4 acc[4][4] = {};

    int srow = (w * 2) * 16 + (lane >> 2);
    int scol = (lane & 3) * 8;
    const __bf16* aptr0 = Ain + (size_t)(m0 + srow) * DIM + scol;
    const __bf16* aptr1 = aptr0 + (size_t)16 * DIM;
    const __bf16* bptr0 = Bt + (size_t)(n0 + srow) * DIM + scol;
    const __bf16* bptr1 = bptr0 + (size_t)16 * DIM;
    int so0 = (w * 2) * 512;
    int so1 = (w * 2 + 1) * 512;

    GLD_LDS16(aptr0, Ab[0] + so0);
    GLD_LDS16(aptr1, Ab[0] + so1);
    GLD_LDS16(bptr0, Bb[0] + so0);
    GLD_LDS16(bptr1, Bb[0] + so1);
    __syncthreads();

    int cur = 0;
    for (int kt = 0; kt < 32; ++kt) {
        int nxt = kt + 1;
        int nb = cur ^ 1;
        if (nxt < 32) {
            int k0 = nxt * 32;
            GLD_LDS16(aptr0 + k0, Ab[nb] + so0);
            GLD_LDS16(aptr1 + k0, Ab[nb] + so1);
            GLD_LDS16(bptr0 + k0, Bb[nb] + so0);
            GLD_LDS16(bptr1 + k0, Bb[nb] + so1);
        }
        bf16x8 af[4], bf[4];
#pragma unroll
        for (int mf = 0; mf < 4; mf++)
            af[mf] = *(bf16x8*)&Ab[cur][(wm + mf * 16 + c) * 32 + g * 8];
#pragma unroll
        for (int nf = 0; nf < 4; nf++)
            bf[nf] = *(bf16x8*)&Bb[cur][(wn + nf * 16 + c) * 32 + g * 8];
#pragma unroll
        for (int mf = 0; mf < 4; mf++)
#pragma unroll
            for (int nf = 0; nf < 4; nf++)
                acc[mf][nf] = mfma16(af[mf], bf[nf], acc[mf][nf]);
        __syncthreads();
        cur = nb;
    }

#pragma unroll
    for (int nf = 0; nf < 4; nf++) {
        int col = n0 + wn + nf * 16 + c;
        float bval = bias[col];
#pragma unroll
        for (int mf = 0; mf < 4; mf++) {
            int row = m0 + wm + mf * 16 + g * 4;
#pragma unroll
            for (int r = 0; r < 4; r++)
                Out[(size_t)(row + r) * DIM + col] = acc[mf][nf][r] + bval;
        }
    }
}

// ---------------------------------------------------------------------------
extern "C" void kernel_launch(void* const* d_in, const int* in_sizes, int n_in,
                              void* d_out, int out_size, void* d_ws, size_t ws_size,
                              hipStream_t stream)
{
    const float* q  = (const float*)d_in[0];
    const float* k  = (const float*)d_in[1];
    const float* v  = (const float*)d_in[2];
    // d_in[3] = mask (known causal; applied analytically)
    const float* Wq = (const float*)d_in[4];
    const float* bq = (const float*)d_in[5];
    const float* Wk = (const float*)d_in[6];
    const float* bk = (const float*)d_in[7];
    const float* Wv = (const float*)d_in[8];
    const float* bv = (const float*)d_in[9];
    const float* Wo = (const float*)d_in[10];
    const float* bo = (const float*)d_in[11];

    char* ws = (char*)d_ws;
    __bf16* wt  = (__bf16*)ws;                             // 8 MB (4 x 2MB)
    __bf16* qp  = (__bf16*)(ws + (size_t)(8u  << 20));     // 16 MB
    __bf16* kp  = (__bf16*)(ws + (size_t)(24u << 20));     // 16 MB
    __bf16* vpT = (__bf16*)(ws + (size_t)(40u << 20));     // 16 MB
    __bf16* ao  = (__bf16*)(ws + (size_t)(56u << 20));     // 16 MB (end: 72MB)

    wt_kernel<<<dim3(16, 16, 4), 256, 0, stream>>>(Wq, Wk, Wv, Wo, wt);
    gemm_proj<<<dim3(64, 8, 3), 256, 0, stream>>>(q, k, v, wt, bq, bk, bv, qp, kp, vpT);
    fa_kernel<<<dim3(2048), 256, 0, stream>>>(qp, kp, vpT, ao);
    gemm_out<<<dim3(64, 8), 256, 0, stream>>>(ao, wt, bo, (float*)d_out);

    (void)in_sizes; (void)n_in; (void)out_size; (void)ws_size;
}